// Round 6
// baseline (644.132 us; speedup 1.0000x reference)
//
#include <hip/hip_runtime.h>
#include <hip/hip_fp16.h>
#include <math.h>

#define N_NODES 50000
#define N_EDGES 1200000
#define N_GRAPHS 128
#define D_IN 32
#define D_H 64
#define D_OUT 10
#define ELL_CAP 64

#define EPS 1e-7f
#define MAX_NORM (1.0f - 1e-5f)

typedef _Float16 half8 __attribute__((ext_vector_type(8)));
typedef float float4v __attribute__((ext_vector_type(4)));

// ---------------- wave helpers ----------------

__device__ __forceinline__ float wave_reduce_sum(float v) {
    #pragma unroll
    for (int off = 32; off > 0; off >>= 1)
        v += __shfl_xor(v, off, 64);
    return v;
}

// logmap0(proj(expmap0(u))) on a 64-lane-distributed vector (one component
// per lane; inactive lanes pass 0). Replicates the reference's op sequence.
__device__ __forceinline__ float exp_proj_log(float m) {
    float n = fmaxf(sqrtf(wave_reduce_sum(m * m)), EPS);
    float v = tanhf(n) * m / n;
    float nv = fmaxf(sqrtf(wave_reduce_sum(v * v)), EPS);
    if (nv > MAX_NORM) v = v * (MAX_NORM / nv);
    float nl = sqrtf(wave_reduce_sum(v * v));
    nl = fminf(fmaxf(nl, EPS), MAX_NORM);
    return atanhf(nl) * v / nl;
}

// ---------------- kernels ----------------

// Build ELL adjacency (ushort src ids): append src[e] to dst[e]'s row.
__global__ void ell_fill_kernel(const int* __restrict__ src, const int* __restrict__ dst,
                                int* __restrict__ deg, ushort* __restrict__ ell, int E) {
    int e = blockIdx.x * 256 + threadIdx.x;
    if (e >= E) return;
    int s = src[e];
    int d = dst[e];
    s = min(max(s, 0), N_NODES - 1);
    d = min(max(d, 0), N_NODES - 1);
    int pos = atomicAdd(&deg[d], 1);
    if (pos < ELL_CAP) ell[d * ELL_CAP + pos] = (ushort)s;
}

// u0 = fp16(logmap0(proj(expmap0(x)))), x: [N, 32]. One wave per node.
__global__ void tangent0_kernel(const float* __restrict__ x, __half* __restrict__ u0, int n) {
    int gid = blockIdx.x * 256 + threadIdx.x;
    int node = gid >> 6;
    int lane = gid & 63;
    if (node >= n) return;
    float m = (lane < D_IN) ? x[node * D_IN + lane] : 0.0f;
    float t = exp_proj_log(m);
    if (lane < D_IN) u0[node * D_IN + lane] = __float2half(t);
}

// Repack W (f32 [K,64]) into B-fragment order for mfma_f32_16x16x32_f16:
// Whf[((jb*NF + f)*64 + lane)*8 + j] = W[f*32 + (lane>>4)*8 + j][jb*16 + (lane&15)]
template <int K>
__global__ void repack_kernel(const float* __restrict__ W, __half* __restrict__ Whf) {
    const int NF = K / 32;
    int idx = blockIdx.x * 256 + threadIdx.x;
    if (idx >= 4 * NF * 64 * 8) return;
    int j = idx & 7;
    int lane = (idx >> 3) & 63;
    int f = (idx >> 9) % NF;
    int jb = (idx >> 9) / NF;
    int k = f * 32 + ((lane >> 4) * 8) + j;
    int n = jb * 16 + (lane & 15);
    Whf[idx] = __float2half(W[k * 64 + n]);
}

// t[N,64] fp32 = u[N,K] fp16 @ W + b via MFMA. One wave = 16 nodes x 16 cols.
// A-frag: A[m=lane&15][k=(lane>>4)*8+j], loaded as contiguous half8 straight
// from the row-major fp16 table. Output stored fp32 (gather wants fp32 rows).
template <int K>
__global__ void gemm_kernel(const __half* __restrict__ u, const __half* __restrict__ Whf,
                            const float* __restrict__ b, float* __restrict__ t) {
    const int NF = K / 32;
    int gw = blockIdx.x * 4 + (threadIdx.x >> 6);
    int lane = threadIdx.x & 63;
    int jb = gw & 3;
    int tile = gw >> 2;
    int node0 = tile * 16;
    if (node0 >= N_NODES) return;
    int m = lane & 15, quad = lane >> 4;

    float4v acc = {0.f, 0.f, 0.f, 0.f};
    const half8* bfr = (const half8*)Whf + (size_t)(jb * NF) * 64 + lane;
    #pragma unroll
    for (int f = 0; f < NF; ++f) {
        half8 a = *(const half8*)(u + (size_t)(node0 + m) * K + f * 32 + quad * 8);
        half8 bb = bfr[f * 64];
        acc = __builtin_amdgcn_mfma_f32_16x16x32_f16(a, bb, acc, 0, 0, 0);
    }
    int j = jb * 16 + m;
    float bias = b[j];
    #pragma unroll
    for (int r = 0; r < 4; ++r) {
        int node = node0 + quad * 4 + r;   // C/D: col=lane&15, row=quad*4+reg
        t[node * 64 + j] = acc[r] + bias;
    }
}

// Gather-mean over ELL -> act -> expmap0 -> proj -> logmap0 -> fp16 store
// or atomic pool. ONE WAVE PER NODE, lane = feature dim; R2-proven pattern:
// uniform-index __shfl (lowers to readlane, no LDS pipe) + 4 independent
// fp32 loads in flight per iteration (MLP hides random-gather latency).
template <int ACT, int POOL>
__global__ void agg_kernel(const float* __restrict__ t, const int* __restrict__ deg,
                           const ushort* __restrict__ ell, __half* __restrict__ uout,
                           const int* __restrict__ batch, float* __restrict__ pooled,
                           float* __restrict__ cntg) {
    int node = blockIdx.x * 4 + (threadIdx.x >> 6);
    int lane = threadIdx.x & 63;
    if (node >= N_NODES) return;
    int dt = deg[node];
    int d = min(dt, ELL_CAP);
    // one coalesced 128B load: lane e holds neighbor id e
    int id = (lane < d) ? (int)ell[node * ELL_CAP + lane] : 0;

    float acc = 0.0f;
    int e = 0;
    for (; e + 4 <= d; e += 4) {
        int s0 = __shfl(id, e, 64);
        int s1 = __shfl(id, e + 1, 64);
        int s2 = __shfl(id, e + 2, 64);
        int s3 = __shfl(id, e + 3, 64);
        float v0 = t[s0 * 64 + lane];
        float v1 = t[s1 * 64 + lane];
        float v2 = t[s2 * 64 + lane];
        float v3 = t[s3 * 64 + lane];
        acc += v0 + v1 + v2 + v3;
    }
    for (; e < d; ++e) {
        int s = __shfl(id, e, 64);
        acc += t[s * 64 + lane];
    }

    float m = acc / fmaxf((float)dt, 1.0f);
    if (ACT) m = (m >= 0.0f) ? m : 0.2f * m;
    float r = exp_proj_log(m);

    if (POOL) {
        int g = min(max(batch[node], 0), N_GRAPHS - 1);
        atomicAdd(&pooled[g * 64 + lane], r);
        if (lane == 0) atomicAdd(&cntg[g], 1.0f);
    } else {
        uout[node * 64 + lane] = __float2half(r);
    }
}

// final head: mean -> exp/proj/log -> @Wl + bl -> expmap0 -> proj
__global__ void head_kernel(const float* __restrict__ pooled, const float* __restrict__ cntg,
                            const float* __restrict__ Wl, const float* __restrict__ bl,
                            float* __restrict__ out) {
    int g = blockIdx.x;
    int lane = threadIdx.x;
    float m = pooled[g * 64 + lane] / fmaxf(cntg[g], 1.0f);
    float z = exp_proj_log(m);
    float acc = 0.0f;
    #pragma unroll
    for (int k = 0; k < 64; ++k) {
        float zk = __shfl(z, k, 64);
        if (lane < D_OUT) acc = fmaf(zk, Wl[k * D_OUT + lane], acc);
    }
    float o = (lane < D_OUT) ? (acc + bl[lane]) : 0.0f;
    float n = fmaxf(sqrtf(wave_reduce_sum(o * o)), EPS);
    float v = tanhf(n) * o / n;
    float nv = fmaxf(sqrtf(wave_reduce_sum(v * v)), EPS);
    if (nv > MAX_NORM) v = v * (MAX_NORM / nv);
    if (lane < D_OUT) out[g * D_OUT + lane] = v;
}

// ---------------- launch ----------------

extern "C" void kernel_launch(void* const* d_in, const int* in_sizes, int n_in,
                              void* d_out, int out_size, void* d_ws, size_t ws_size,
                              hipStream_t stream) {
    const float* x   = (const float*)d_in[0];
    const int* edge  = (const int*)d_in[1];   // [2, E]
    const int* batch = (const int*)d_in[2];
    const float* W1  = (const float*)d_in[3];
    const float* b1  = (const float*)d_in[4];
    const float* W2  = (const float*)d_in[5];
    const float* b2  = (const float*)d_in[6];
    const float* W3  = (const float*)d_in[7];
    const float* b3  = (const float*)d_in[8];
    const float* Wl  = (const float*)d_in[9];
    const float* bl  = (const float*)d_in[10];
    float* out = (float*)d_out;

    const int N = N_NODES, E = N_EDGES, G = N_GRAPHS;
    const int* src = edge;
    const int* dst = edge + E;

    // ws layout: [deg:int N][pooled:f G*64][cntg:f G][ell:u16 N*64]
    //            [u0h:h N*32][u1h:h N*64][u2h:h N*64][t:f N*64][Wh1][Wh2][Wh3]
    char* ws = (char*)d_ws;
    int*    deg    = (int*)ws;
    float*  pooled = (float*)(deg + N);
    float*  cntg   = pooled + (size_t)G * 64;
    ushort* ell    = (ushort*)(cntg + G);
    __half* u0h    = (__half*)(ell + (size_t)N * ELL_CAP);
    __half* u1h    = u0h + (size_t)N * 32;
    __half* u2h    = u1h + (size_t)N * 64;
    float*  t      = (float*)(u2h + (size_t)N * 64);
    __half* Wh1    = (__half*)(t + (size_t)N * 64);   // 2048
    __half* Wh2    = Wh1 + 2048;                      // 4096
    __half* Wh3    = Wh2 + 4096;                      // 4096

    size_t zero_bytes = ((size_t)N + (size_t)G * 64 + G) * 4;
    hipMemsetAsync(d_ws, 0, zero_bytes, stream);

    int blocksE   = (E + 255) / 256;
    int blocksN64 = (N * 64 + 255) / 256;   // one wave per node, 4 per block
    int blocksG   = 3125;                   // 50000/16 tiles * 4 col-waves / 4 per block

    repack_kernel<32><<<8,  256, 0, stream>>>(W1, Wh1);
    repack_kernel<64><<<16, 256, 0, stream>>>(W2, Wh2);
    repack_kernel<64><<<16, 256, 0, stream>>>(W3, Wh3);
    ell_fill_kernel<<<blocksE, 256, 0, stream>>>(src, dst, deg, ell, E);
    tangent0_kernel<<<blocksN64, 256, 0, stream>>>(x, u0h, N);

    // layer 1: t = u0@W1+b1 (MFMA, fp32 out); gather-mean -> lrelu -> epl -> u1h
    gemm_kernel<32><<<blocksG, 256, 0, stream>>>(u0h, Wh1, b1, t);
    agg_kernel<1, 0><<<blocksN64, 256, 0, stream>>>(t, deg, ell, u1h, nullptr, nullptr, nullptr);
    // layer 2
    gemm_kernel<64><<<blocksG, 256, 0, stream>>>(u1h, Wh2, b2, t);
    agg_kernel<1, 0><<<blocksN64, 256, 0, stream>>>(t, deg, ell, u2h, nullptr, nullptr, nullptr);
    // layer 3 (no act) + fused pooling
    gemm_kernel<64><<<blocksG, 256, 0, stream>>>(u2h, Wh3, b3, t);
    agg_kernel<0, 1><<<blocksN64, 256, 0, stream>>>(t, deg, ell, nullptr, batch, pooled, cntg);

    head_kernel<<<G, 64, 0, stream>>>(pooled, cntg, Wl, bl, out);
}

// Round 7
// 444.221 us; speedup vs baseline: 1.4500x; 1.4500x over previous
//
#include <hip/hip_runtime.h>
#include <hip/hip_fp16.h>
#include <math.h>

#define N_NODES 50000
#define N_EDGES 1200000
#define N_GRAPHS 128
#define D_IN 32
#define D_H 64
#define D_OUT 10
#define ELL_CAP 64

#define EPS 1e-7f
#define MAX_NORM (1.0f - 1e-5f)

typedef _Float16 half8 __attribute__((ext_vector_type(8)));
typedef float float4v __attribute__((ext_vector_type(4)));

// ---------------- wave helpers ----------------

__device__ __forceinline__ float wave_reduce_sum(float v) {
    #pragma unroll
    for (int off = 32; off > 0; off >>= 1)
        v += __shfl_xor(v, off, 64);
    return v;
}

// logmap0(proj(expmap0(u))) on a 64-lane-distributed vector (one component
// per lane; inactive lanes pass 0). Replicates the reference's op sequence.
__device__ __forceinline__ float exp_proj_log(float m) {
    float n = fmaxf(sqrtf(wave_reduce_sum(m * m)), EPS);
    float v = tanhf(n) * m / n;
    float nv = fmaxf(sqrtf(wave_reduce_sum(v * v)), EPS);
    if (nv > MAX_NORM) v = v * (MAX_NORM / nv);
    float nl = sqrtf(wave_reduce_sum(v * v));
    nl = fminf(fmaxf(nl, EPS), MAX_NORM);
    return atanhf(nl) * v / nl;
}

// ---------------- kernels ----------------

// Build ELL adjacency (ushort src ids): append src[e] to dst[e]'s row.
__global__ void ell_fill_kernel(const int* __restrict__ src, const int* __restrict__ dst,
                                int* __restrict__ deg, ushort* __restrict__ ell, int E) {
    int e = blockIdx.x * 256 + threadIdx.x;
    if (e >= E) return;
    int s = src[e];
    int d = dst[e];
    s = min(max(s, 0), N_NODES - 1);
    d = min(max(d, 0), N_NODES - 1);
    int pos = atomicAdd(&deg[d], 1);
    if (pos < ELL_CAP) ell[d * ELL_CAP + pos] = (ushort)s;
}

// u0 = fp16(logmap0(proj(expmap0(x)))), x: [N, 32]. One wave per node.
__global__ void tangent0_kernel(const float* __restrict__ x, __half* __restrict__ u0, int n) {
    int gid = blockIdx.x * 256 + threadIdx.x;
    int node = gid >> 6;
    int lane = gid & 63;
    if (node >= n) return;
    float m = (lane < D_IN) ? x[node * D_IN + lane] : 0.0f;
    float t = exp_proj_log(m);
    if (lane < D_IN) u0[node * D_IN + lane] = __float2half(t);
}

// Repack W (f32 [K,64]) into B-fragment order for mfma_f32_16x16x32_f16:
// Whf[((jb*NF + f)*64 + lane)*8 + j] = W[f*32 + (lane>>4)*8 + j][jb*16 + (lane&15)]
template <int K>
__global__ void repack_kernel(const float* __restrict__ W, __half* __restrict__ Whf) {
    const int NF = K / 32;
    int idx = blockIdx.x * 256 + threadIdx.x;
    if (idx >= 4 * NF * 64 * 8) return;
    int j = idx & 7;
    int lane = (idx >> 3) & 63;
    int f = (idx >> 9) % NF;
    int jb = (idx >> 9) / NF;
    int k = f * 32 + ((lane >> 4) * 8) + j;
    int n = jb * 16 + (lane & 15);
    Whf[idx] = __float2half(W[k * 64 + n]);
}

// t[N,64] fp32 = u[N,K] fp16 @ W + b via MFMA. One wave = 16 nodes x 16 cols.
// A-frag: A[m=lane&15][k=(lane>>4)*8+j], loaded as contiguous half8 straight
// from the row-major fp16 table. Output stored fp32 (gather wants fp32 rows).
template <int K>
__global__ void gemm_kernel(const __half* __restrict__ u, const __half* __restrict__ Whf,
                            const float* __restrict__ b, float* __restrict__ t) {
    const int NF = K / 32;
    int gw = blockIdx.x * 4 + (threadIdx.x >> 6);
    int lane = threadIdx.x & 63;
    int jb = gw & 3;
    int tile = gw >> 2;
    int node0 = tile * 16;
    if (node0 >= N_NODES) return;
    int m = lane & 15, quad = lane >> 4;

    float4v acc = {0.f, 0.f, 0.f, 0.f};
    const half8* bfr = (const half8*)Whf + (size_t)(jb * NF) * 64 + lane;
    #pragma unroll
    for (int f = 0; f < NF; ++f) {
        half8 a = *(const half8*)(u + (size_t)(node0 + m) * K + f * 32 + quad * 8);
        half8 bb = bfr[f * 64];
        acc = __builtin_amdgcn_mfma_f32_16x16x32_f16(a, bb, acc, 0, 0, 0);
    }
    int j = jb * 16 + m;
    float bias = b[j];
    #pragma unroll
    for (int r = 0; r < 4; ++r) {
        int node = node0 + quad * 4 + r;   // C/D: col=lane&15, row=quad*4+reg
        t[node * 64 + j] = acc[r] + bias;
    }
}

// Gather-mean over ELL -> act -> expmap0 -> proj -> logmap0 -> fp16 store,
// or (POOL) block-level LDS combine + one atomic burst per block.
// ONE WAVE PER NODE, lane = feature dim; uniform-index __shfl + 4 loads in
// flight. NOTE: N_NODES % 4 == 0, so with POOL no wave exits early (barrier).
template <int ACT, int POOL>
__global__ void agg_kernel(const float* __restrict__ t, const int* __restrict__ deg,
                           const ushort* __restrict__ ell, __half* __restrict__ uout,
                           const int* __restrict__ batch, float* __restrict__ pooled,
                           float* __restrict__ cntg) {
    __shared__ float rs[4][64];
    __shared__ int gs[4];
    int widx = threadIdx.x >> 6;
    int lane = threadIdx.x & 63;
    int node = blockIdx.x * 4 + widx;
    if (node >= N_NODES) return;   // never taken when POOL (50000 % 4 == 0)
    int dt = deg[node];
    int d = min(dt, ELL_CAP);
    // one coalesced 128B load: lane e holds neighbor id e
    int id = (lane < d) ? (int)ell[node * ELL_CAP + lane] : 0;

    float acc = 0.0f;
    int e = 0;
    for (; e + 4 <= d; e += 4) {
        int s0 = __shfl(id, e, 64);
        int s1 = __shfl(id, e + 1, 64);
        int s2 = __shfl(id, e + 2, 64);
        int s3 = __shfl(id, e + 3, 64);
        float v0 = t[s0 * 64 + lane];
        float v1 = t[s1 * 64 + lane];
        float v2 = t[s2 * 64 + lane];
        float v3 = t[s3 * 64 + lane];
        acc += v0 + v1 + v2 + v3;
    }
    for (; e < d; ++e) {
        int s = __shfl(id, e, 64);
        acc += t[s * 64 + lane];
    }

    float m = acc / fmaxf((float)dt, 1.0f);
    if (ACT) m = (m >= 0.0f) ? m : 0.2f * m;
    float r = exp_proj_log(m);

    if (POOL) {
        int g = min(max(batch[node], 0), N_GRAPHS - 1);
        rs[widx][lane] = r;
        if (lane == 0) gs[widx] = g;
        __syncthreads();
        int g0 = gs[0], g1 = gs[1], g2 = gs[2], g3 = gs[3];
        bool uni = (g0 == g1) && (g1 == g2) && (g2 == g3);
        if (uni) {
            // sorted batch -> ~99% of blocks take this path: 1 burst / block
            if (widx == 0) {
                float s = rs[0][lane] + rs[1][lane] + rs[2][lane] + rs[3][lane];
                atomicAdd(&pooled[g0 * 64 + lane], s);
                if (lane == 0) atomicAdd(&cntg[g0], 4.0f);
            }
        } else {
            atomicAdd(&pooled[g * 64 + lane], r);
            if (lane == 0) atomicAdd(&cntg[g], 1.0f);
        }
    } else {
        uout[node * 64 + lane] = __float2half(r);
    }
}

// final head: mean -> exp/proj/log -> @Wl + bl -> expmap0 -> proj
__global__ void head_kernel(const float* __restrict__ pooled, const float* __restrict__ cntg,
                            const float* __restrict__ Wl, const float* __restrict__ bl,
                            float* __restrict__ out) {
    int g = blockIdx.x;
    int lane = threadIdx.x;
    float m = pooled[g * 64 + lane] / fmaxf(cntg[g], 1.0f);
    float z = exp_proj_log(m);
    float acc = 0.0f;
    #pragma unroll
    for (int k = 0; k < 64; ++k) {
        float zk = __shfl(z, k, 64);
        if (lane < D_OUT) acc = fmaf(zk, Wl[k * D_OUT + lane], acc);
    }
    float o = (lane < D_OUT) ? (acc + bl[lane]) : 0.0f;
    float n = fmaxf(sqrtf(wave_reduce_sum(o * o)), EPS);
    float v = tanhf(n) * o / n;
    float nv = fmaxf(sqrtf(wave_reduce_sum(v * v)), EPS);
    if (nv > MAX_NORM) v = v * (MAX_NORM / nv);
    if (lane < D_OUT) out[g * D_OUT + lane] = v;
}

// ---------------- launch ----------------

extern "C" void kernel_launch(void* const* d_in, const int* in_sizes, int n_in,
                              void* d_out, int out_size, void* d_ws, size_t ws_size,
                              hipStream_t stream) {
    const float* x   = (const float*)d_in[0];
    const int* edge  = (const int*)d_in[1];   // [2, E]
    const int* batch = (const int*)d_in[2];
    const float* W1  = (const float*)d_in[3];
    const float* b1  = (const float*)d_in[4];
    const float* W2  = (const float*)d_in[5];
    const float* b2  = (const float*)d_in[6];
    const float* W3  = (const float*)d_in[7];
    const float* b3  = (const float*)d_in[8];
    const float* Wl  = (const float*)d_in[9];
    const float* bl  = (const float*)d_in[10];
    float* out = (float*)d_out;

    const int N = N_NODES, E = N_EDGES, G = N_GRAPHS;
    const int* src = edge;
    const int* dst = edge + E;

    // ws layout: [deg:int N][pooled:f G*64][cntg:f G][ell:u16 N*64]
    //            [u0h:h N*32][u1h:h N*64][u2h:h N*64][t:f N*64][Wh1][Wh2][Wh3]
    char* ws = (char*)d_ws;
    int*    deg    = (int*)ws;
    float*  pooled = (float*)(deg + N);
    float*  cntg   = pooled + (size_t)G * 64;
    ushort* ell    = (ushort*)(cntg + G);
    __half* u0h    = (__half*)(ell + (size_t)N * ELL_CAP);
    __half* u1h    = u0h + (size_t)N * 32;
    __half* u2h    = u1h + (size_t)N * 64;
    float*  t      = (float*)(u2h + (size_t)N * 64);
    __half* Wh1    = (__half*)(t + (size_t)N * 64);   // 2048
    __half* Wh2    = Wh1 + 2048;                      // 4096
    __half* Wh3    = Wh2 + 4096;                      // 4096

    size_t zero_bytes = ((size_t)N + (size_t)G * 64 + G) * 4;
    hipMemsetAsync(d_ws, 0, zero_bytes, stream);

    int blocksE   = (E + 255) / 256;
    int blocksN64 = (N * 64 + 255) / 256;   // one wave per node, 4 per block
    int blocksG   = 3125;                   // 50000/16 tiles * 4 col-waves / 4 per block

    repack_kernel<32><<<8,  256, 0, stream>>>(W1, Wh1);
    repack_kernel<64><<<16, 256, 0, stream>>>(W2, Wh2);
    repack_kernel<64><<<16, 256, 0, stream>>>(W3, Wh3);
    ell_fill_kernel<<<blocksE, 256, 0, stream>>>(src, dst, deg, ell, E);
    tangent0_kernel<<<blocksN64, 256, 0, stream>>>(x, u0h, N);

    // layer 1: t = u0@W1+b1 (MFMA, fp32 out); gather-mean -> lrelu -> epl -> u1h
    gemm_kernel<32><<<blocksG, 256, 0, stream>>>(u0h, Wh1, b1, t);
    agg_kernel<1, 0><<<blocksN64, 256, 0, stream>>>(t, deg, ell, u1h, nullptr, nullptr, nullptr);
    // layer 2
    gemm_kernel<64><<<blocksG, 256, 0, stream>>>(u1h, Wh2, b2, t);
    agg_kernel<1, 0><<<blocksN64, 256, 0, stream>>>(t, deg, ell, u2h, nullptr, nullptr, nullptr);
    // layer 3 (no act) + LDS-combined pooling
    gemm_kernel<64><<<blocksG, 256, 0, stream>>>(u2h, Wh3, b3, t);
    agg_kernel<0, 1><<<blocksN64, 256, 0, stream>>>(t, deg, ell, nullptr, batch, pooled, cntg);

    head_kernel<<<G, 64, 0, stream>>>(pooled, cntg, Wl, bl, out);
}

// Round 8
// 398.842 us; speedup vs baseline: 1.6150x; 1.1138x over previous
//
#include <hip/hip_runtime.h>
#include <hip/hip_fp16.h>
#include <math.h>

#define N_NODES 50000
#define N_EDGES 1200000
#define N_GRAPHS 128
#define D_IN 32
#define D_H 64
#define D_OUT 10
#define ELL_CAP 64

#define EPS 1e-7f
#define MAX_NORM (1.0f - 1e-5f)

typedef _Float16 half8 __attribute__((ext_vector_type(8)));
typedef float float4v __attribute__((ext_vector_type(4)));

// ---------------- wave helpers ----------------

__device__ __forceinline__ float wave_reduce_sum(float v) {
    #pragma unroll
    for (int off = 32; off > 0; off >>= 1)
        v += __shfl_xor(v, off, 64);
    return v;
}

// logmap0(proj(expmap0(u))) on a 64-lane-distributed vector (one component
// per lane; inactive lanes pass 0). Replicates the reference's op sequence.
__device__ __forceinline__ float exp_proj_log(float m) {
    float n = fmaxf(sqrtf(wave_reduce_sum(m * m)), EPS);
    float v = tanhf(n) * m / n;
    float nv = fmaxf(sqrtf(wave_reduce_sum(v * v)), EPS);
    if (nv > MAX_NORM) v = v * (MAX_NORM / nv);
    float nl = sqrtf(wave_reduce_sum(v * v));
    nl = fminf(fmaxf(nl, EPS), MAX_NORM);
    return atanhf(nl) * v / nl;
}

// ---------------- kernels ----------------

// Build ELL adjacency (ushort src ids): append src[e] to dst[e]'s row.
__global__ void ell_fill_kernel(const int* __restrict__ src, const int* __restrict__ dst,
                                int* __restrict__ deg, ushort* __restrict__ ell, int E) {
    int e = blockIdx.x * 256 + threadIdx.x;
    if (e >= E) return;
    int s = src[e];
    int d = dst[e];
    s = min(max(s, 0), N_NODES - 1);
    d = min(max(d, 0), N_NODES - 1);
    int pos = atomicAdd(&deg[d], 1);
    if (pos < ELL_CAP) ell[d * ELL_CAP + pos] = (ushort)s;
}

// u0 = fp16(logmap0(proj(expmap0(x)))), x: [N, 32]. One wave per node.
__global__ void tangent0_kernel(const float* __restrict__ x, __half* __restrict__ u0, int n) {
    int gid = blockIdx.x * 256 + threadIdx.x;
    int node = gid >> 6;
    int lane = gid & 63;
    if (node >= n) return;
    float m = (lane < D_IN) ? x[node * D_IN + lane] : 0.0f;
    float t = exp_proj_log(m);
    if (lane < D_IN) u0[node * D_IN + lane] = __float2half(t);
}

// Repack W (f32 [K,64]) into B-fragment order for mfma_f32_16x16x32_f16:
// Whf[((jb*NF + f)*64 + lane)*8 + j] = W[f*32 + (lane>>4)*8 + j][jb*16 + (lane&15)]
template <int K>
__global__ void repack_kernel(const float* __restrict__ W, __half* __restrict__ Whf) {
    const int NF = K / 32;
    int idx = blockIdx.x * 256 + threadIdx.x;
    if (idx >= 4 * NF * 64 * 8) return;
    int j = idx & 7;
    int lane = (idx >> 3) & 63;
    int f = (idx >> 9) % NF;
    int jb = (idx >> 9) / NF;
    int k = f * 32 + ((lane >> 4) * 8) + j;
    int n = jb * 16 + (lane & 15);
    Whf[idx] = __float2half(W[k * 64 + n]);
}

// t[N,64] fp16 = u[N,K] fp16 @ W + b via MFMA. One wave = 16 nodes x 16 cols.
// A-frag: A[m=lane&15][k=(lane>>4)*8+j], loaded as contiguous half8 straight
// from the row-major fp16 table.
template <int K>
__global__ void gemm_kernel(const __half* __restrict__ u, const __half* __restrict__ Whf,
                            const float* __restrict__ b, __half* __restrict__ t) {
    const int NF = K / 32;
    int gw = blockIdx.x * 4 + (threadIdx.x >> 6);
    int lane = threadIdx.x & 63;
    int jb = gw & 3;
    int tile = gw >> 2;
    int node0 = tile * 16;
    if (node0 >= N_NODES) return;
    int m = lane & 15, quad = lane >> 4;

    float4v acc = {0.f, 0.f, 0.f, 0.f};
    const half8* bfr = (const half8*)Whf + (size_t)(jb * NF) * 64 + lane;
    #pragma unroll
    for (int f = 0; f < NF; ++f) {
        half8 a = *(const half8*)(u + (size_t)(node0 + m) * K + f * 32 + quad * 8);
        half8 bb = bfr[f * 64];
        acc = __builtin_amdgcn_mfma_f32_16x16x32_f16(a, bb, acc, 0, 0, 0);
    }
    int j = jb * 16 + m;
    float bias = b[j];
    #pragma unroll
    for (int r = 0; r < 4; ++r) {
        int node = node0 + quad * 4 + r;   // C/D: col=lane&15, row=quad*4+reg
        t[node * 64 + j] = __float2half(acc[r] + bias);
    }
}

// Gather-mean over ELL (fp16 rows, 128B each) -> act -> expmap0 -> proj ->
// logmap0 -> fp16 store, or (POOL) block-level LDS combine + one atomic
// burst per block. ONE WAVE PER NODE, lane = feature dim; uniform-index
// __shfl (readlane, no LDS pipe) + EIGHT independent loads in flight.
template <int ACT, int POOL>
__global__ void agg_kernel(const __half* __restrict__ t, const int* __restrict__ deg,
                           const ushort* __restrict__ ell, __half* __restrict__ uout,
                           const int* __restrict__ batch, float* __restrict__ pooled,
                           float* __restrict__ cntg) {
    __shared__ float rs[4][64];
    __shared__ int gs[4];
    int widx = threadIdx.x >> 6;
    int lane = threadIdx.x & 63;
    int node = blockIdx.x * 4 + widx;
    if (node >= N_NODES) return;   // never taken when POOL (50000 % 4 == 0)
    int dt = deg[node];
    int d = min(dt, ELL_CAP);
    // one coalesced 128B load: lane e holds neighbor id e
    int id = (lane < d) ? (int)ell[node * ELL_CAP + lane] : 0;

    float acc = 0.0f;
    int e = 0;
    for (; e + 8 <= d; e += 8) {   // 8 loads in flight (MLP vs random-miss latency)
        int s0 = __shfl(id, e, 64);
        int s1 = __shfl(id, e + 1, 64);
        int s2 = __shfl(id, e + 2, 64);
        int s3 = __shfl(id, e + 3, 64);
        int s4 = __shfl(id, e + 4, 64);
        int s5 = __shfl(id, e + 5, 64);
        int s6 = __shfl(id, e + 6, 64);
        int s7 = __shfl(id, e + 7, 64);
        float v0 = __half2float(t[s0 * 64 + lane]);
        float v1 = __half2float(t[s1 * 64 + lane]);
        float v2 = __half2float(t[s2 * 64 + lane]);
        float v3 = __half2float(t[s3 * 64 + lane]);
        float v4 = __half2float(t[s4 * 64 + lane]);
        float v5 = __half2float(t[s5 * 64 + lane]);
        float v6 = __half2float(t[s6 * 64 + lane]);
        float v7 = __half2float(t[s7 * 64 + lane]);
        acc += ((v0 + v1) + (v2 + v3)) + ((v4 + v5) + (v6 + v7));
    }
    if (e + 4 <= d) {
        int s0 = __shfl(id, e, 64);
        int s1 = __shfl(id, e + 1, 64);
        int s2 = __shfl(id, e + 2, 64);
        int s3 = __shfl(id, e + 3, 64);
        float v0 = __half2float(t[s0 * 64 + lane]);
        float v1 = __half2float(t[s1 * 64 + lane]);
        float v2 = __half2float(t[s2 * 64 + lane]);
        float v3 = __half2float(t[s3 * 64 + lane]);
        acc += (v0 + v1) + (v2 + v3);
        e += 4;
    }
    for (; e < d; ++e) {
        int s = __shfl(id, e, 64);
        acc += __half2float(t[s * 64 + lane]);
    }

    float m = acc / fmaxf((float)dt, 1.0f);
    if (ACT) m = (m >= 0.0f) ? m : 0.2f * m;
    float r = exp_proj_log(m);

    if (POOL) {
        int g = min(max(batch[node], 0), N_GRAPHS - 1);
        rs[widx][lane] = r;
        if (lane == 0) gs[widx] = g;
        __syncthreads();
        int g0 = gs[0], g1 = gs[1], g2 = gs[2], g3 = gs[3];
        bool uni = (g0 == g1) && (g1 == g2) && (g2 == g3);
        if (uni) {
            // sorted batch -> ~99% of blocks: one 64-lane burst per block
            if (widx == 0) {
                float s = rs[0][lane] + rs[1][lane] + rs[2][lane] + rs[3][lane];
                atomicAdd(&pooled[g0 * 64 + lane], s);
                if (lane == 0) atomicAdd(&cntg[g0], 4.0f);
            }
        } else {
            atomicAdd(&pooled[g * 64 + lane], r);
            if (lane == 0) atomicAdd(&cntg[g], 1.0f);
        }
    } else {
        uout[node * 64 + lane] = __float2half(r);
    }
}

// final head: mean -> exp/proj/log -> @Wl + bl -> expmap0 -> proj
__global__ void head_kernel(const float* __restrict__ pooled, const float* __restrict__ cntg,
                            const float* __restrict__ Wl, const float* __restrict__ bl,
                            float* __restrict__ out) {
    int g = blockIdx.x;
    int lane = threadIdx.x;
    float m = pooled[g * 64 + lane] / fmaxf(cntg[g], 1.0f);
    float z = exp_proj_log(m);
    float acc = 0.0f;
    #pragma unroll
    for (int k = 0; k < 64; ++k) {
        float zk = __shfl(z, k, 64);
        if (lane < D_OUT) acc = fmaf(zk, Wl[k * D_OUT + lane], acc);
    }
    float o = (lane < D_OUT) ? (acc + bl[lane]) : 0.0f;
    float n = fmaxf(sqrtf(wave_reduce_sum(o * o)), EPS);
    float v = tanhf(n) * o / n;
    float nv = fmaxf(sqrtf(wave_reduce_sum(v * v)), EPS);
    if (nv > MAX_NORM) v = v * (MAX_NORM / nv);
    if (lane < D_OUT) out[g * D_OUT + lane] = v;
}

// ---------------- launch ----------------

extern "C" void kernel_launch(void* const* d_in, const int* in_sizes, int n_in,
                              void* d_out, int out_size, void* d_ws, size_t ws_size,
                              hipStream_t stream) {
    const float* x   = (const float*)d_in[0];
    const int* edge  = (const int*)d_in[1];   // [2, E]
    const int* batch = (const int*)d_in[2];
    const float* W1  = (const float*)d_in[3];
    const float* b1  = (const float*)d_in[4];
    const float* W2  = (const float*)d_in[5];
    const float* b2  = (const float*)d_in[6];
    const float* W3  = (const float*)d_in[7];
    const float* b3  = (const float*)d_in[8];
    const float* Wl  = (const float*)d_in[9];
    const float* bl  = (const float*)d_in[10];
    float* out = (float*)d_out;

    const int N = N_NODES, E = N_EDGES, G = N_GRAPHS;
    const int* src = edge;
    const int* dst = edge + E;

    // ws layout: [deg:int N][pooled:f G*64][cntg:f G][ell:u16 N*64]
    //            [u0h:h N*32][u1h:h N*64][u2h:h N*64][th:h N*64][Wh1][Wh2][Wh3]
    char* ws = (char*)d_ws;
    int*    deg    = (int*)ws;
    float*  pooled = (float*)(deg + N);
    float*  cntg   = pooled + (size_t)G * 64;
    ushort* ell    = (ushort*)(cntg + G);
    __half* u0h    = (__half*)(ell + (size_t)N * ELL_CAP);
    __half* u1h    = u0h + (size_t)N * 32;
    __half* u2h    = u1h + (size_t)N * 64;
    __half* th     = u2h + (size_t)N * 64;
    __half* Wh1    = th + (size_t)N * 64;     // 2048
    __half* Wh2    = Wh1 + 2048;              // 4096
    __half* Wh3    = Wh2 + 4096;              // 4096

    size_t zero_bytes = ((size_t)N + (size_t)G * 64 + G) * 4;
    hipMemsetAsync(d_ws, 0, zero_bytes, stream);

    int blocksE   = (E + 255) / 256;
    int blocksN64 = (N * 64 + 255) / 256;   // one wave per node, 4 per block
    int blocksG   = 3125;                   // 50000/16 tiles * 4 col-waves / 4 per block

    repack_kernel<32><<<8,  256, 0, stream>>>(W1, Wh1);
    repack_kernel<64><<<16, 256, 0, stream>>>(W2, Wh2);
    repack_kernel<64><<<16, 256, 0, stream>>>(W3, Wh3);
    ell_fill_kernel<<<blocksE, 256, 0, stream>>>(src, dst, deg, ell, E);
    tangent0_kernel<<<blocksN64, 256, 0, stream>>>(x, u0h, N);

    // layer 1: t = u0@W1+b1 (MFMA, fp16 out); gather-mean -> lrelu -> epl -> u1h
    gemm_kernel<32><<<blocksG, 256, 0, stream>>>(u0h, Wh1, b1, th);
    agg_kernel<1, 0><<<blocksN64, 256, 0, stream>>>(th, deg, ell, u1h, nullptr, nullptr, nullptr);
    // layer 2
    gemm_kernel<64><<<blocksG, 256, 0, stream>>>(u1h, Wh2, b2, th);
    agg_kernel<1, 0><<<blocksN64, 256, 0, stream>>>(th, deg, ell, u2h, nullptr, nullptr, nullptr);
    // layer 3 (no act) + LDS-combined pooling
    gemm_kernel<64><<<blocksG, 256, 0, stream>>>(u2h, Wh3, b3, th);
    agg_kernel<0, 1><<<blocksN64, 256, 0, stream>>>(th, deg, ell, nullptr, batch, pooled, cntg);

    head_kernel<<<G, 64, 0, stream>>>(pooled, cntg, Wl, bl, out);
}

// Round 9
// 396.184 us; speedup vs baseline: 1.6258x; 1.0067x over previous
//
#include <hip/hip_runtime.h>
#include <hip/hip_fp16.h>
#include <math.h>

#define N_NODES 50000
#define N_EDGES 1200000
#define N_GRAPHS 128
#define D_IN 32
#define D_H 64
#define D_OUT 10
#define ELL_CAP 64
#define EQ (N_EDGES / 4)          // 300000, edges per ILP slot

#define EPS 1e-7f
#define MAX_NORM (1.0f - 1e-5f)

typedef _Float16 half8 __attribute__((ext_vector_type(8)));
typedef float float4v __attribute__((ext_vector_type(4)));

// ---------------- wave helpers ----------------

__device__ __forceinline__ float wave_reduce_sum(float v) {
    #pragma unroll
    for (int off = 32; off > 0; off >>= 1)
        v += __shfl_xor(v, off, 64);
    return v;
}

// sum over the 32 lanes of each half (halves hold identical data -> both
// halves end with the full sum)
__device__ __forceinline__ float reduce32(float v) {
    #pragma unroll
    for (int off = 16; off > 0; off >>= 1)
        v += __shfl_xor(v, off, 64);
    return v;
}

// logmap0(proj(expmap0(u))) on a 64-lane-distributed vector.
__device__ __forceinline__ float exp_proj_log(float m) {
    float n = fmaxf(sqrtf(wave_reduce_sum(m * m)), EPS);
    float v = tanhf(n) * m / n;
    float nv = fmaxf(sqrtf(wave_reduce_sum(v * v)), EPS);
    if (nv > MAX_NORM) v = v * (MAX_NORM / nv);
    float nl = sqrtf(wave_reduce_sum(v * v));
    nl = fminf(fmaxf(nl, EPS), MAX_NORM);
    return atanhf(nl) * v / nl;
}

// ---------------- kernels ----------------

// Fused: [blocks 0..EB) ELL build, 4 independent edges per thread (ILP on
// the atomic-return chain); [EB..) tangent0 = fp16(logmap0(proj(expmap0(x)))).
#define EB ((EQ + 255) / 256)
__global__ void build_kernel(const int* __restrict__ src, const int* __restrict__ dst,
                             int* __restrict__ deg, ushort* __restrict__ ell,
                             const float* __restrict__ x, __half* __restrict__ u0) {
    if (blockIdx.x < EB) {
        int tid = blockIdx.x * 256 + threadIdx.x;
        if (tid < EQ) {
            #pragma unroll
            for (int q = 0; q < 4; ++q) {
                int e = tid + q * EQ;
                int s = src[e];
                int d = dst[e];
                s = min(max(s, 0), N_NODES - 1);
                d = min(max(d, 0), N_NODES - 1);
                int pos = atomicAdd(&deg[d], 1);
                if (pos < ELL_CAP) ell[d * ELL_CAP + pos] = (ushort)s;
            }
        }
    } else {
        int gid = (blockIdx.x - EB) * 256 + threadIdx.x;
        int node = gid >> 6;
        int lane = gid & 63;
        if (node >= N_NODES) return;
        float m = (lane < D_IN) ? x[node * D_IN + lane] : 0.0f;
        float t = exp_proj_log(m);
        if (lane < D_IN) u0[node * D_IN + lane] = __float2half(t);
    }
}

// Repack W (f32 [K,64]) into B-fragment order for mfma_f32_16x16x32_f16:
// Whf[((jb*NF + f)*64 + lane)*8 + j] = W[f*32 + (lane>>4)*8 + j][jb*16 + (lane&15)]
template <int K>
__global__ void repack_kernel(const float* __restrict__ W, __half* __restrict__ Whf) {
    const int NF = K / 32;
    int idx = blockIdx.x * 256 + threadIdx.x;
    if (idx >= 4 * NF * 64 * 8) return;
    int j = idx & 7;
    int lane = (idx >> 3) & 63;
    int f = (idx >> 9) % NF;
    int jb = (idx >> 9) / NF;
    int k = f * 32 + ((lane >> 4) * 8) + j;
    int n = jb * 16 + (lane & 15);
    Whf[idx] = __float2half(W[k * 64 + n]);
}

// t[N,64] fp16 = u[N,K] fp16 @ W + b via MFMA. One wave = 16 nodes x 16 cols.
template <int K>
__global__ void gemm_kernel(const __half* __restrict__ u, const __half* __restrict__ Whf,
                            const float* __restrict__ b, __half* __restrict__ t) {
    const int NF = K / 32;
    int gw = blockIdx.x * 4 + (threadIdx.x >> 6);
    int lane = threadIdx.x & 63;
    int jb = gw & 3;
    int tile = gw >> 2;
    int node0 = tile * 16;
    if (node0 >= N_NODES) return;
    int m = lane & 15, quad = lane >> 4;

    float4v acc = {0.f, 0.f, 0.f, 0.f};
    const half8* bfr = (const half8*)Whf + (size_t)(jb * NF) * 64 + lane;
    #pragma unroll
    for (int f = 0; f < NF; ++f) {
        half8 a = *(const half8*)(u + (size_t)(node0 + m) * K + f * 32 + quad * 8);
        half8 bb = bfr[f * 64];
        acc = __builtin_amdgcn_mfma_f32_16x16x32_f16(a, bb, acc, 0, 0, 0);
    }
    int j = jb * 16 + m;
    float bias = b[j];
    #pragma unroll
    for (int r = 0; r < 4; ++r) {
        int node = node0 + quad * 4 + r;   // C/D: col=lane&15, row=quad*4+reg
        t[node * 64 + j] = __float2half(acc[r] + bias);
    }
}

// Gather-mean over ELL: DUAL-EDGE half2 pattern — half-wave per edge, lane
// owns dims (2*d2, 2*d2+1). Edge ids come from UNIFORM readlanes; the
// half-select is a v_cndmask (NO divergent-index shuffle — R5's mistake).
// 4 loads in flight cover 8 edges. Then act -> expmap0 -> proj -> logmap0
// -> fp16 store, or (POOL) block LDS combine + one atomic burst per block.
template <int ACT, int POOL>
__global__ void agg_kernel(const __half* __restrict__ t, const int* __restrict__ deg,
                           const ushort* __restrict__ ell, __half* __restrict__ uout,
                           const int* __restrict__ batch, float* __restrict__ pooled,
                           float* __restrict__ cntg) {
    __shared__ float rs[4][64];
    __shared__ int gs[4];
    int widx = threadIdx.x >> 6;
    int lane = threadIdx.x & 63;
    int node = blockIdx.x * 4 + widx;
    if (node >= N_NODES) return;   // never taken when POOL (50000 % 4 == 0)
    bool lo = lane < 32;
    int d2 = lane & 31;
    int dt = deg[node];
    int d = min(dt, ELL_CAP);
    // one coalesced 128B load: lane e holds neighbor id e
    int id = (lane < d) ? (int)ell[node * ELL_CAP + lane] : 0;
    const __half2* t2 = (const __half2*)t;

    float ax = 0.f, ay = 0.f;
    int e = 0;
    for (; e + 8 <= d; e += 8) {   // 8 edges, 4 wave-loads in flight
        int sA0 = __shfl(id, e, 64),     sB0 = __shfl(id, e + 1, 64);
        int sA1 = __shfl(id, e + 2, 64), sB1 = __shfl(id, e + 3, 64);
        int sA2 = __shfl(id, e + 4, 64), sB2 = __shfl(id, e + 5, 64);
        int sA3 = __shfl(id, e + 6, 64), sB3 = __shfl(id, e + 7, 64);
        int s0 = lo ? sA0 : sB0;
        int s1 = lo ? sA1 : sB1;
        int s2 = lo ? sA2 : sB2;
        int s3 = lo ? sA3 : sB3;
        float2 f0 = __half22float2(t2[s0 * 32 + d2]);
        float2 f1 = __half22float2(t2[s1 * 32 + d2]);
        float2 f2 = __half22float2(t2[s2 * 32 + d2]);
        float2 f3 = __half22float2(t2[s3 * 32 + d2]);
        ax += (f0.x + f1.x) + (f2.x + f3.x);
        ay += (f0.y + f1.y) + (f2.y + f3.y);
    }
    for (; e + 2 <= d; e += 2) {
        int sA = __shfl(id, e, 64), sB = __shfl(id, e + 1, 64);
        int s = lo ? sA : sB;
        float2 f = __half22float2(t2[s * 32 + d2]);
        ax += f.x; ay += f.y;
    }
    if (e < d) {                   // odd leftover: half 0 only
        int s = __shfl(id, e, 64);
        if (lo) {
            float2 f = __half22float2(t2[s * 32 + d2]);
            ax += f.x; ay += f.y;
        }
    }
    ax += __shfl_xor(ax, 32, 64);  // combine halves; both now hold full sums
    ay += __shfl_xor(ay, 32, 64);

    float inv = 1.0f / fmaxf((float)dt, 1.0f);
    float mx = ax * inv, my = ay * inv;
    if (ACT) {
        mx = (mx >= 0.f) ? mx : 0.2f * mx;
        my = (my >= 0.f) ? my : 0.2f * my;
    }
    // expmap0 -> proj -> logmap0 on the dim pair (32-lane reductions)
    float n = fmaxf(sqrtf(reduce32(mx * mx + my * my)), EPS);
    float s = tanhf(n) / n;
    float vx = s * mx, vy = s * my;
    float nv = fmaxf(sqrtf(reduce32(vx * vx + vy * vy)), EPS);
    if (nv > MAX_NORM) { float sc = MAX_NORM / nv; vx *= sc; vy *= sc; }
    float nl = sqrtf(reduce32(vx * vx + vy * vy));
    nl = fminf(fmaxf(nl, EPS), MAX_NORM);
    float sl = atanhf(nl) / nl;
    float rx = sl * vx, ry = sl * vy;

    if (POOL) {
        int g = min(max(batch[node], 0), N_GRAPHS - 1);
        if (lo) { rs[widx][2 * d2] = rx; rs[widx][2 * d2 + 1] = ry; }
        if (lane == 0) gs[widx] = g;
        __syncthreads();
        int g0 = gs[0], g1 = gs[1], g2 = gs[2], g3 = gs[3];
        bool uni = (g0 == g1) && (g1 == g2) && (g2 == g3);
        if (uni) {
            // sorted batch -> ~99% of blocks: one 64-lane burst per block
            if (widx == 0) {
                float sum = rs[0][lane] + rs[1][lane] + rs[2][lane] + rs[3][lane];
                atomicAdd(&pooled[g0 * 64 + lane], sum);
                if (lane == 0) atomicAdd(&cntg[g0], 4.0f);
            }
        } else {
            if (lo) {
                atomicAdd(&pooled[g * 64 + 2 * d2], rx);
                atomicAdd(&pooled[g * 64 + 2 * d2 + 1], ry);
            }
            if (lane == 0) atomicAdd(&cntg[g], 1.0f);
        }
    } else {
        if (lo) ((__half2*)uout)[node * 32 + d2] = __floats2half2_rn(rx, ry);
    }
}

// final head: mean -> exp/proj/log -> @Wl + bl -> expmap0 -> proj
__global__ void head_kernel(const float* __restrict__ pooled, const float* __restrict__ cntg,
                            const float* __restrict__ Wl, const float* __restrict__ bl,
                            float* __restrict__ out) {
    int g = blockIdx.x;
    int lane = threadIdx.x;
    float m = pooled[g * 64 + lane] / fmaxf(cntg[g], 1.0f);
    float z = exp_proj_log(m);
    float acc = 0.0f;
    #pragma unroll
    for (int k = 0; k < 64; ++k) {
        float zk = __shfl(z, k, 64);
        if (lane < D_OUT) acc = fmaf(zk, Wl[k * D_OUT + lane], acc);
    }
    float o = (lane < D_OUT) ? (acc + bl[lane]) : 0.0f;
    float n = fmaxf(sqrtf(wave_reduce_sum(o * o)), EPS);
    float v = tanhf(n) * o / n;
    float nv = fmaxf(sqrtf(wave_reduce_sum(v * v)), EPS);
    if (nv > MAX_NORM) v = v * (MAX_NORM / nv);
    if (lane < D_OUT) out[g * D_OUT + lane] = v;
}

// ---------------- launch ----------------

extern "C" void kernel_launch(void* const* d_in, const int* in_sizes, int n_in,
                              void* d_out, int out_size, void* d_ws, size_t ws_size,
                              hipStream_t stream) {
    const float* x   = (const float*)d_in[0];
    const int* edge  = (const int*)d_in[1];   // [2, E]
    const int* batch = (const int*)d_in[2];
    const float* W1  = (const float*)d_in[3];
    const float* b1  = (const float*)d_in[4];
    const float* W2  = (const float*)d_in[5];
    const float* b2  = (const float*)d_in[6];
    const float* W3  = (const float*)d_in[7];
    const float* b3  = (const float*)d_in[8];
    const float* Wl  = (const float*)d_in[9];
    const float* bl  = (const float*)d_in[10];
    float* out = (float*)d_out;

    const int N = N_NODES, E = N_EDGES, G = N_GRAPHS;
    const int* src = edge;
    const int* dst = edge + E;

    // ws layout: [deg:int N][pooled:f G*64][cntg:f G][ell:u16 N*64]
    //            [u0h:h N*32][u1h:h N*64][u2h:h N*64][th:h N*64][Wh1][Wh2][Wh3]
    char* ws = (char*)d_ws;
    int*    deg    = (int*)ws;
    float*  pooled = (float*)(deg + N);
    float*  cntg   = pooled + (size_t)G * 64;
    ushort* ell    = (ushort*)(cntg + G);
    __half* u0h    = (__half*)(ell + (size_t)N * ELL_CAP);
    __half* u1h    = u0h + (size_t)N * 32;
    __half* u2h    = u1h + (size_t)N * 64;
    __half* th     = u2h + (size_t)N * 64;
    __half* Wh1    = th + (size_t)N * 64;     // 2048
    __half* Wh2    = Wh1 + 2048;              // 4096
    __half* Wh3    = Wh2 + 4096;              // 4096

    size_t zero_bytes = ((size_t)N + (size_t)G * 64 + G) * 4;
    hipMemsetAsync(d_ws, 0, zero_bytes, stream);

    int blocksN64 = (N * 64 + 255) / 256;   // one wave per node, 4 per block
    int blocksB   = EB + blocksN64;         // fused build: edges first, then tangent0
    int blocksG   = 3125;                   // 50000/16 tiles * 4 col-waves / 4 per block

    repack_kernel<32><<<8,  256, 0, stream>>>(W1, Wh1);
    repack_kernel<64><<<16, 256, 0, stream>>>(W2, Wh2);
    repack_kernel<64><<<16, 256, 0, stream>>>(W3, Wh3);
    build_kernel<<<blocksB, 256, 0, stream>>>(src, dst, deg, ell, x, u0h);

    // layer 1: t = u0@W1+b1 (MFMA, fp16 out); gather-mean -> lrelu -> epl -> u1h
    gemm_kernel<32><<<blocksG, 256, 0, stream>>>(u0h, Wh1, b1, th);
    agg_kernel<1, 0><<<blocksN64, 256, 0, stream>>>(th, deg, ell, u1h, nullptr, nullptr, nullptr);
    // layer 2
    gemm_kernel<64><<<blocksG, 256, 0, stream>>>(u1h, Wh2, b2, th);
    agg_kernel<1, 0><<<blocksN64, 256, 0, stream>>>(th, deg, ell, u2h, nullptr, nullptr, nullptr);
    // layer 3 (no act) + LDS-combined pooling
    gemm_kernel<64><<<blocksG, 256, 0, stream>>>(u2h, Wh3, b3, th);
    agg_kernel<0, 1><<<blocksN64, 256, 0, stream>>>(th, deg, ell, nullptr, batch, pooled, cntg);

    head_kernel<<<G, 64, 0, stream>>>(pooled, cntg, Wl, bl, out);
}